// Round 13
// baseline (5120.504 us; speedup 1.0000x reference)
//
#include <hip/hip_runtime.h>
#include <cstdint>
#include <cstddef>

typedef __attribute__((ext_vector_type(8))) __bf16 bf16x8;
typedef __attribute__((ext_vector_type(8))) unsigned short u16x8;
typedef __attribute__((ext_vector_type(4))) unsigned short u16x4;
typedef __attribute__((ext_vector_type(2))) unsigned short u16x2;
typedef __attribute__((ext_vector_type(4))) float f32x4;
typedef __attribute__((ext_vector_type(2))) float f32x2;

// ---- helpers -------------------------------------------------------------
__device__ __forceinline__ unsigned short f2bf(float f){
  unsigned int u = __float_as_uint(f);
  u += 0x7FFFu + ((u >> 16) & 1u);          // round to nearest even
  return (unsigned short)(u >> 16);
}
__device__ __forceinline__ float bf2f(unsigned short s){
  return __uint_as_float(((unsigned int)s) << 16);
}
__device__ __forceinline__ float sigm(float x){ return 1.f/(1.f + __expf(-x)); }
__device__ __forceinline__ float tanh_f(float x){ float e = __expf(2.f*x); return 1.f - 2.f/(e + 1.f); }
__device__ __forceinline__ f32x4 mfma16(u16x8 a, u16x8 b, f32x4 c){
  return __builtin_amdgcn_mfma_f32_16x16x32_bf16(
      __builtin_bit_cast(bf16x8, a), __builtin_bit_cast(bf16x8, b), c, 0, 0, 0);
}

// B=1024, T=128, F=128, H=256
// Wc(256x1024), gate g cols [g*256,(g+1)*256):
//   g=0: Wih_h_r + Whh_r ; g=1: Wih_h_z + Whh_z ; g=2: Wih_h_n ; g=3: Whh_n
//
// seq11: COLUMN-SPLIT + per-step group sync.
//   Measured wall (rounds 6-10): per-CU L2 load BW ~24 B/cy -> streaming any
//   weights caps a 64-CU design at ~6.4us/step. Fix: 256 WGs = 64 batch-
//   groups x 4 unit-groups. WG(b,k): rows 16b..16b+15, units 64k..64k+63.
//   Its Wc slice (4 gates x 64 units x K256 = 128 KB) is FULLY LDS-resident
//   -> zero steady-state weight traffic. Per step, the 4 WGs of group b
//   exchange decayed-h quarters via an 8KB global buffer + release/acquire
//   flag sync (agent scope = cross-XCD correct; bid=k*64+b puts the group
//   on one XCD under %8 round-robin as a latency heuristic only).
//   hbuf lives in d_out's h_final region, GROUP-PRIVATE bytes (h_final
//   overwrites it at t=127 strictly after that group's last hbuf read).
//   flags live in the dead W2sw region, zeroed per launch via memset.

__device__ __forceinline__ float wcval(int g, int n, int k,
    const float* __restrict__ Wih, const float* __restrict__ Whh){
  if (g==0) return Wih[n*512 + 128+k]       + Whh[n*256 + k];
  if (g==1) return Wih[(256+n)*512 + 128+k] + Whh[(256+n)*256 + k];
  if (g==2) return Wih[(512+n)*512 + 128+k];
  return Whh[(512+n)*256 + k];
}

// ---- weight prep ---------------------------------------------------------
// Wsl : ((k*16 + g*4 + ut)*8 + ks)*512 + l*8 + j   (262144 elems, 512 KB)
//       B-frag of Wc gate g, units k*64+ut*16..+15, k-rows ks*32..+31
// W2  : [nt(48)][ks(8)][lane(64)][8]   (gi_pre GEMM)
// Wd  : [nt(16)][ks(4)][lane(64)][8]   (gamma GEMM)
__global__ __launch_bounds__(256) void kw(
    const float* __restrict__ Wdh, const float* __restrict__ Wih,
    const float* __restrict__ Whh, const float* __restrict__ bih,
    const float* __restrict__ bhh,
    unsigned short* __restrict__ Wsl,
    unsigned short* __restrict__ W2,
    unsigned short* __restrict__ Wd, float* __restrict__ b2){
  int i0 = blockIdx.x*256 + threadIdx.x;
  int stride = gridDim.x*256;
  for (int idx=i0; idx<262144; idx+=stride){          // Wsl (all of Wc)
    int j=idx&7, l=(idx>>3)&63, r=idx>>9;             // r < 512
    int ks=r&7, q2=r>>3;                              // q2 = k*16+g*4+ut
    int ut=q2&3, g=(q2>>2)&3, k=q2>>4;
    int n = k*64 + ut*16 + (l&15);                    // within-gate col [0,256)
    int kk = ks*32 + ((l>>4)<<3) + j;
    Wsl[idx] = f2bf(wcval(g, n, kk, Wih, Whh));
  }
  for (int idx=i0; idx<196608; idx+=stride){
    int j=idx&7, l=(idx>>3)&63, ks=(idx>>9)&7, nt=idx>>12;
    int n = nt*16 + (l&15);
    int k = ks*32 + ((l>>4)<<3) + j;
    float v = (k<128) ? Wih[n*512 + k] : Wih[n*512 + 256 + k];
    W2[idx] = f2bf(v);
  }
  for (int idx=i0; idx<32768; idx+=stride){
    int j=idx&7, l=(idx>>3)&63, ks=(idx>>9)&3, nt=idx>>11;
    int n = nt*16 + (l&15);
    int k = ks*32 + ((l>>4)<<3) + j;
    Wd[idx] = f2bf(Wdh[n*128 + k]);
  }
  for (int idx=i0; idx<768; idx+=stride)
    b2[idx] = bih[idx] + (idx<512 ? bhh[idx] : 0.f);
}

// ---- elementwise prep: Apre=[x_in|m] (T,B,256) bf16 ; Dt=(T,B,128) bf16 --
__global__ __launch_bounds__(256) void kprep(
    const float* __restrict__ X, const float* __restrict__ M,
    const float* __restrict__ D, const float* __restrict__ mu,
    const float* __restrict__ Xl, const float* __restrict__ Wdx,
    const float* __restrict__ bdx,
    unsigned short* __restrict__ Apre, unsigned short* __restrict__ Dt){
  int lane = threadIdx.x & 63;
  int wave = (blockIdx.x*256 + threadIdx.x) >> 6;
  int c0 = lane*2;
  float dg0 = Wdx[c0*128 + c0];
  float dg1 = Wdx[(c0+1)*128 + (c0+1)];
  float bx0 = bdx[c0], bx1 = bdx[c0+1];
  for (int r = wave; r < 131072; r += 4096){
    int t = r>>10, b = r&1023;
    size_t src = ((size_t)b*128 + t)*128 + c0;
    f32x2 x  = *(const f32x2*)(X+src);
    f32x2 m  = *(const f32x2*)(M+src);
    f32x2 d  = *(const f32x2*)(D+src);
    f32x2 xl = *(const f32x2*)(Xl+src);
    f32x2 mb = *(const f32x2*)(mu + b*128 + c0);
    float g0 = __expf(-fmaxf(0.f, d.x*dg0 + bx0));
    float g1 = __expf(-fmaxf(0.f, d.y*dg1 + bx1));
    float xh0 = g0*xl.x + (1.f-g0)*mb.x;
    float xh1 = g1*xl.y + (1.f-g1)*mb.y;
    float xi0 = m.x*x.x + (1.f-m.x)*xh0;
    float xi1 = m.y*x.y + (1.f-m.y)*xh1;
    size_t ar = (size_t)r*256;
    *(u16x2*)(Apre + ar + c0)        = u16x2{f2bf(xi0), f2bf(xi1)};
    *(u16x2*)(Apre + ar + 128 + c0)  = u16x2{f2bf(m.x), f2bf(m.y)};
    *(u16x2*)(Dt + (size_t)r*128 + c0) = u16x2{f2bf(d.x), f2bf(d.y)};
  }
}

// ---- batched activation GEMM (unchanged, verified) -----------------------
template<int KS, int NTOT, int PNT, int MODE>
__global__ __launch_bounds__(256) void gemm_act(
    const unsigned short* __restrict__ A, const unsigned short* __restrict__ Bw,
    const float* __restrict__ bias, unsigned short* __restrict__ out){
  const int N = NTOT*16;
  int lane = threadIdx.x & 63;
  int wid  = threadIdx.x >> 6;
  int gw   = blockIdx.x*4 + wid;
  size_t rb = (size_t)gw*32;
  int lr = lane&15, lk = (lane>>4)<<3, lq = (lane>>4)<<2;
  u16x8 a[2][KS];
  #pragma unroll
  for (int mt=0; mt<2; ++mt)
    #pragma unroll
    for (int ks=0; ks<KS; ++ks)
      a[mt][ks] = *(const u16x8*)&A[(rb + mt*16 + lr)*(KS*32) + ks*32 + lk];
  #pragma unroll
  for (int p=0; p<NTOT/PNT; ++p){
    f32x4 acc[2][PNT];
    #pragma unroll
    for (int mt=0; mt<2; ++mt)
      #pragma unroll
      for (int i=0; i<PNT; ++i) acc[mt][i] = f32x4{0.f,0.f,0.f,0.f};
    #pragma unroll
    for (int ks=0; ks<KS; ++ks){
      #pragma unroll
      for (int i=0; i<PNT; ++i){
        int nt = p*PNT + i;
        u16x8 b = *(const u16x8*)&Bw[((size_t)(nt*KS + ks)*64 + lane)*8];
        acc[0][i] = mfma16(a[0][ks], b, acc[0][i]);
        acc[1][i] = mfma16(a[1][ks], b, acc[1][i]);
      }
    }
    #pragma unroll
    for (int i=0; i<PNT; ++i){
      int nt = p*PNT + i; int col = nt*16 + lr;
      float bv = bias[col];
      #pragma unroll
      for (int mt=0; mt<2; ++mt){
        #pragma unroll
        for (int q=0; q<4; ++q){
          size_t row = rb + mt*16 + lq + q;
          float v = acc[mt][i][q] + bv;
          if (MODE==1) v = __expf(-fmaxf(0.f, v));
          out[row*N + col] = f2bf(v);
        }
      }
    }
  }
}

// ---- persistent sequential kernel: col-split, all-LDS weights ------------
__global__ __launch_bounds__(256) void seq11(
    const unsigned short* __restrict__ WslG,
    const unsigned short* __restrict__ gamma, const unsigned short* __restrict__ gipre,
    const float* __restrict__ bhh, unsigned int* __restrict__ flags,
    float* __restrict__ out){
  extern __shared__ char smem[];
  unsigned short* Wlds = (unsigned short*)smem;            // 131072 B (Wc slice)
  unsigned short* hsw  = (unsigned short*)(smem + 131072); //   8192 B (full h)
  const int tid  = threadIdx.x;
  const int lane = tid & 63;
  const int w    = tid >> 6;              // 0..3 (unit-tile within slice)
  const int bid  = blockIdx.x;
  const int b    = bid & 63;              // batch group (rows 16b..16b+15)
  const int k    = bid >> 6;              // unit group (units 64k..64k+63)
  const int lr   = lane & 15;
  const int lq4  = (lane >> 4) << 2;      // row quad base
  const int u    = k*64 + w*16 + lr;      // this thread's hidden unit

  // hbuf: group-private 16 KB inside d_out's h_final region
  unsigned short* hb_base =
      (unsigned short*)((char*)out + 134217728) + b*8192;  // u16 units

  // ---- prologue: Wc slice -> LDS (128 KB, resident forever) ----
  {
    const u16x8* src = (const u16x8*)(WslG + (size_t)k*65536);
    u16x8* dst = (u16x8*)Wlds;
    for (int i = tid; i < 8192; i += 256) dst[i] = src[i];
  }

  float h_reg[4];
  #pragma unroll
  for (int q=0; q<4; ++q) h_reg[q] = 0.f;
  const float bnn = bhh[512 + u];

  unsigned short g_pre[4];
  #pragma unroll
  for (int q=0; q<4; ++q)
    g_pre[q] = gamma[((size_t)(b*16 + lq4 + q))*256 + u];

  // hbuf positions for this thread's 4 (row, u) elems (fragment order)
  int hp[4];
  #pragma unroll
  for (int q=0; q<4; ++q)
    hp[q] = (u>>5)*512 + ((lq4+q) + (((u>>3)&3)<<4))*8 + (u&7);

  __syncthreads();   // Wlds ready

  for (int t = 0; t < 128; ++t){
    unsigned short* hb = hb_base + (t&1)*4096;
    // ---- stage 1: decay own quarter, write rep + hbuf quarter ----
    #pragma unroll
    for (int q=0; q<4; ++q){
      float hd = h_reg[q] * bf2f(g_pre[q]);
      h_reg[q] = hd;
      out[((size_t)(b*16+lq4+q)*128 + t)*256 + u] = hd;
      hb[hp[q]] = f2bf(hd);
    }
    __syncthreads();   // all quarters issued (per-wave vmcnt drained)

    // ---- stage 2: group sync (release/acquire, agent scope) ----
    if (tid == 0){
      __hip_atomic_fetch_add(&flags[b*128 + t], 1u,
                             __ATOMIC_RELEASE, __HIP_MEMORY_SCOPE_AGENT);
      unsigned int c = 0;
      while (__hip_atomic_load(&flags[b*128 + t],
                               __ATOMIC_RELAXED, __HIP_MEMORY_SCOPE_AGENT) < 4u){
        if (++c > 30000000u) break;       // bounded: no hangs
      }
    }
    __threadfence();   // acquire: invalidate stale L1/L2 lines
    __syncthreads();

    // ---- stage 3: full h (all 4 quarters) -> hsw LDS ----
    {
      const u16x8* src = (const u16x8*)hb;
      u16x8* dst = (u16x8*)hsw;
      dst[tid*2]   = src[tid*2];
      dst[tid*2+1] = src[tid*2+1];
    }
    __syncthreads();   // hsw ready

    // ---- stage 4: prefetch gate inputs under MFMA cover ----
    const unsigned short* gp = gipre + ((size_t)t*1024 + b*16)*768;
    unsigned short gv[3][4];
    #pragma unroll
    for (int g3=0; g3<3; ++g3)
      #pragma unroll
      for (int q=0; q<4; ++q)
        gv[g3][q] = gp[(size_t)(lq4+q)*768 + g3*256 + u];
    if (t < 127){
      #pragma unroll
      for (int q=0; q<4; ++q)
        g_pre[q] = gamma[((size_t)(t+1)*1024 + b*16 + lq4 + q)*256 + u];
    }

    // ---- stage 5: MFMA — all weights in LDS, 32 MFMAs/wave ----
    f32x4 acc[4];
    #pragma unroll
    for (int g=0; g<4; ++g) acc[g] = f32x4{0.f,0.f,0.f,0.f};
    #pragma unroll
    for (int ks=0; ks<8; ++ks){
      u16x8 a = *(const u16x8*)&hsw[(ks*64 + lane)*8];
      #pragma unroll
      for (int g=0; g<4; ++g){
        u16x8 bb = *(const u16x8*)&Wlds[(((g*4 + w)*8 + ks)*64 + lane)*8];
        acc[g] = mfma16(a, bb, acc[g]);
      }
    }

    // ---- stage 6: gate phase (thread owns unit u, rows lq4..lq4+3) ----
    #pragma unroll
    for (int q=0; q<4; ++q){
      float gr = bf2f(gv[0][q]);
      float gz = bf2f(gv[1][q]);
      float gn = bf2f(gv[2][q]);
      float rr = sigm(gr + acc[0][q]);
      float zz = sigm(gz + acc[1][q]);
      float nv = tanh_f(gn + acc[2][q] + rr*(acc[3][q] + bnn));
      float hn = (1.f-zz)*nv + zz*h_reg[q];
      h_reg[q] = hn;
      if (t == 127) out[(size_t)33554432 + (size_t)(b*16+lq4+q)*256 + u] = hn;
    }
  }
}

// ---- host glue -----------------------------------------------------------
extern "C" void kernel_launch(void* const* d_in, const int* in_sizes, int n_in,
                              void* d_out, int out_size, void* d_ws, size_t ws_size,
                              hipStream_t stream){
  (void)in_sizes; (void)n_in; (void)out_size; (void)ws_size;
  const float* X   = (const float*)d_in[0];
  const float* M   = (const float*)d_in[1];
  const float* D   = (const float*)d_in[2];
  const float* mu  = (const float*)d_in[3];
  const float* Xl  = (const float*)d_in[4];
  const float* Wdh = (const float*)d_in[5];
  const float* bdh = (const float*)d_in[6];
  const float* Wdx = (const float*)d_in[7];
  const float* bdx = (const float*)d_in[8];
  const float* Wih = (const float*)d_in[9];
  const float* Whh = (const float*)d_in[10];
  const float* bih = (const float*)d_in[11];
  const float* bhh = (const float*)d_in[12];
  float* out = (float*)d_out;
  char* ws = (char*)d_ws;

  // workspace layout (total 269421568 B — identical footprint to round 1)
  unsigned short* gipre = (unsigned short*)ws;                      // 201326592 B
  unsigned short* gamma = (unsigned short*)(ws + 201326592);        //  67108864 B
  unsigned short* W2sw  = (unsigned short*)(ws + 268435456);        //    393216 B
  unsigned short* Wdsw  = (unsigned short*)(ws + 268828672);        //     65536 B
  unsigned short* WslG  = (unsigned short*)(ws + 268894208);        //    524288 B
  float*          b2    = (float*)        (ws + 269418496);         //      3072 B
  // flags (32 KB) overlay W2sw: W2sw is dead once gemm_act<8,48> completes,
  // and the memset below re-zeroes it every launch (deterministic replays).
  unsigned int*   flags = (unsigned int*)(ws + 268435456);
  // Apre (67.1MB) + Dt (33.6MB) staged inside d_out: fully consumed by the
  // GEMMs below BEFORE seq11 writes the real outputs (same-stream ordering).
  unsigned short* Apre = (unsigned short*)d_out;
  unsigned short* Dt   = (unsigned short*)((char*)d_out + 67108864);

  hipFuncSetAttribute(reinterpret_cast<const void*>(seq11),
                      hipFuncAttributeMaxDynamicSharedMemorySize, 139264);

  kw<<<256, 256, 0, stream>>>(Wdh, Wih, Whh, bih, bhh, WslG, W2sw, Wdsw, b2);
  kprep<<<1024, 256, 0, stream>>>(X, M, D, mu, Xl, Wdx, bdx, Apre, Dt);
  gemm_act<4,16,8,1><<<1024, 256, 0, stream>>>(Dt, Wdsw, bdh, gamma);
  gemm_act<8,48,8,0><<<1024, 256, 0, stream>>>(Apre, W2sw, b2, gipre);
  hipMemsetAsync(flags, 0, 32768, stream);   // zero sync flags every launch
  seq11<<<256, 256, 139264, stream>>>(WslG, gamma, gipre, bhh, flags, out);
}

// Round 14
// 1172.416 us; speedup vs baseline: 4.3675x; 4.3675x over previous
//
#include <hip/hip_runtime.h>
#include <cstdint>
#include <cstddef>

typedef __attribute__((ext_vector_type(8))) __bf16 bf16x8;
typedef __attribute__((ext_vector_type(8))) unsigned short u16x8;
typedef __attribute__((ext_vector_type(4))) unsigned short u16x4;
typedef __attribute__((ext_vector_type(2))) unsigned short u16x2;
typedef __attribute__((ext_vector_type(4))) float f32x4;
typedef __attribute__((ext_vector_type(2))) float f32x2;

// ---- helpers -------------------------------------------------------------
__device__ __forceinline__ unsigned short f2bf(float f){
  unsigned int u = __float_as_uint(f);
  u += 0x7FFFu + ((u >> 16) & 1u);          // round to nearest even
  return (unsigned short)(u >> 16);
}
__device__ __forceinline__ float bf2f(unsigned short s){
  return __uint_as_float(((unsigned int)s) << 16);
}
__device__ __forceinline__ float sigm(float x){ return 1.f/(1.f + __expf(-x)); }
__device__ __forceinline__ float tanh_f(float x){ float e = __expf(2.f*x); return 1.f - 2.f/(e + 1.f); }
__device__ __forceinline__ f32x4 mfma16(u16x8 a, u16x8 b, f32x4 c){
  return __builtin_amdgcn_mfma_f32_16x16x32_bf16(
      __builtin_bit_cast(bf16x8, a), __builtin_bit_cast(bf16x8, b), c, 0, 0, 0);
}

// B=1024, T=128, F=128, H=256
// Per step: S = h(16x256 per WG) @ Wc(256x1024); gate g cols [g*256,(g+1)*256):
//   g=0: Wih_h_r + Whh_r ; g=1: Wih_h_z + Whh_z ; g=2: Wih_h_n ; g=3: Whh_n
// seq12: 64 WGs x 512 thr (8 waves), 16 rows/WG, 1 WG/CU.
//   DIAGNOSIS (rounds 6-10): seq step time = 48 streamed chunks/wave x ~325cy
//   = serial load->use chains. Compiler LICM-hoists loop-invariant weight
//   loads, then regalloc remats each at its use -> zero pipelining.
//   FIX: opaque per-iteration offset (asm "+v") makes stream addresses
//   loop-variant -> loads stay in-loop in textual order; 6 batches x 8
//   chunks through 3 rotating reg buffers, 3-deep in flight; automatic
//   counted vmcnt waits give a real pipeline. ks4..5 stay LDS-resident.

__device__ __forceinline__ float wcval(int g, int n, int k,
    const float* __restrict__ Wih, const float* __restrict__ Whh){
  if (g==0) return Wih[n*512 + 128+k]       + Whh[n*256 + k];
  if (g==1) return Wih[(256+n)*512 + 128+k] + Whh[(256+n)*256 + k];
  if (g==2) return Wih[(512+n)*512 + 128+k];
  return Whh[(512+n)*256 + k];
}

// ---- weight prep ---------------------------------------------------------
// WstrG: (((w*6+s)*8+i)*64+l)*8+j   s=0..5 -> ks_eff=[0,1,2,3,6,7][s],
//        g=i>>1, c=i&1, n=(w*2+c)*16+(l&15)   (196608 elems, 384 KB)
// WldsG: (((w*8+g*2+c)*2+ks2)*64+l)*8+j  ks=4+ks2 (65536 elems, 128 KB)
// W2  : [nt(48)][ks(8)][lane(64)][8] ; Wd : [nt(16)][ks(4)][lane(64)][8]
__global__ __launch_bounds__(256) void kw(
    const float* __restrict__ Wdh, const float* __restrict__ Wih,
    const float* __restrict__ Whh, const float* __restrict__ bih,
    const float* __restrict__ bhh,
    unsigned short* __restrict__ WstrG, unsigned short* __restrict__ WldsG,
    unsigned short* __restrict__ W2,
    unsigned short* __restrict__ Wd, float* __restrict__ b2){
  int i0 = blockIdx.x*256 + threadIdx.x;
  int stride = gridDim.x*256;
  for (int idx=i0; idx<196608; idx+=stride){          // WstrG (ks 0..3,6,7)
    int j=idx&7, l=(idx>>3)&63, r=idx>>9;             // r < 384
    int i=r&7, r2=r>>3;                               // r2 = w*6+s
    int s=r2%6, w=r2/6;
    int ks = (s<4) ? s : (s+2);
    int g=i>>1, c=i&1;
    int n = (w*2+c)*16 + (l&15);
    int k = ks*32 + ((l>>4)<<3) + j;
    WstrG[idx] = f2bf(wcval(g, n, k, Wih, Whh));
  }
  for (int idx=i0; idx<65536; idx+=stride){           // WldsG (ks 4..5)
    int j=idx&7, l=(idx>>3)&63, r=idx>>9;             // r < 128
    int ks2=r&1, r2=r>>1;
    int c=r2&1, g=(r2>>1)&3, w=r2>>3;
    int n = (w*2+c)*16 + (l&15);
    int k = (4+ks2)*32 + ((l>>4)<<3) + j;
    WldsG[idx] = f2bf(wcval(g, n, k, Wih, Whh));
  }
  for (int idx=i0; idx<196608; idx+=stride){
    int j=idx&7, l=(idx>>3)&63, ks=(idx>>9)&7, nt=idx>>12;
    int n = nt*16 + (l&15);
    int k = ks*32 + ((l>>4)<<3) + j;
    float v = (k<128) ? Wih[n*512 + k] : Wih[n*512 + 256 + k];
    W2[idx] = f2bf(v);
  }
  for (int idx=i0; idx<32768; idx+=stride){
    int j=idx&7, l=(idx>>3)&63, ks=(idx>>9)&3, nt=idx>>11;
    int n = nt*16 + (l&15);
    int k = ks*32 + ((l>>4)<<3) + j;
    Wd[idx] = f2bf(Wdh[n*128 + k]);
  }
  for (int idx=i0; idx<768; idx+=stride)
    b2[idx] = bih[idx] + (idx<512 ? bhh[idx] : 0.f);
}

// ---- elementwise prep (unchanged, verified) ------------------------------
__global__ __launch_bounds__(256) void kprep(
    const float* __restrict__ X, const float* __restrict__ M,
    const float* __restrict__ D, const float* __restrict__ mu,
    const float* __restrict__ Xl, const float* __restrict__ Wdx,
    const float* __restrict__ bdx,
    unsigned short* __restrict__ Apre, unsigned short* __restrict__ Dt){
  int lane = threadIdx.x & 63;
  int wave = (blockIdx.x*256 + threadIdx.x) >> 6;
  int c0 = lane*2;
  float dg0 = Wdx[c0*128 + c0];
  float dg1 = Wdx[(c0+1)*128 + (c0+1)];
  float bx0 = bdx[c0], bx1 = bdx[c0+1];
  for (int r = wave; r < 131072; r += 4096){
    int t = r>>10, b = r&1023;
    size_t src = ((size_t)b*128 + t)*128 + c0;
    f32x2 x  = *(const f32x2*)(X+src);
    f32x2 m  = *(const f32x2*)(M+src);
    f32x2 d  = *(const f32x2*)(D+src);
    f32x2 xl = *(const f32x2*)(Xl+src);
    f32x2 mb = *(const f32x2*)(mu + b*128 + c0);
    float g0 = __expf(-fmaxf(0.f, d.x*dg0 + bx0));
    float g1 = __expf(-fmaxf(0.f, d.y*dg1 + bx1));
    float xh0 = g0*xl.x + (1.f-g0)*mb.x;
    float xh1 = g1*xl.y + (1.f-g1)*mb.y;
    float xi0 = m.x*x.x + (1.f-m.x)*xh0;
    float xi1 = m.y*x.y + (1.f-m.y)*xh1;
    size_t ar = (size_t)r*256;
    *(u16x2*)(Apre + ar + c0)        = u16x2{f2bf(xi0), f2bf(xi1)};
    *(u16x2*)(Apre + ar + 128 + c0)  = u16x2{f2bf(m.x), f2bf(m.y)};
    *(u16x2*)(Dt + (size_t)r*128 + c0) = u16x2{f2bf(d.x), f2bf(d.y)};
  }
}

// ---- batched activation GEMM (unchanged, verified) -----------------------
template<int KS, int NTOT, int PNT, int MODE>
__global__ __launch_bounds__(256) void gemm_act(
    const unsigned short* __restrict__ A, const unsigned short* __restrict__ Bw,
    const float* __restrict__ bias, unsigned short* __restrict__ out){
  const int N = NTOT*16;
  int lane = threadIdx.x & 63;
  int wid  = threadIdx.x >> 6;
  int gw   = blockIdx.x*4 + wid;
  size_t rb = (size_t)gw*32;
  int lr = lane&15, lk = (lane>>4)<<3, lq = (lane>>4)<<2;
  u16x8 a[2][KS];
  #pragma unroll
  for (int mt=0; mt<2; ++mt)
    #pragma unroll
    for (int ks=0; ks<KS; ++ks)
      a[mt][ks] = *(const u16x8*)&A[(rb + mt*16 + lr)*(KS*32) + ks*32 + lk];
  #pragma unroll
  for (int p=0; p<NTOT/PNT; ++p){
    f32x4 acc[2][PNT];
    #pragma unroll
    for (int mt=0; mt<2; ++mt)
      #pragma unroll
      for (int i=0; i<PNT; ++i) acc[mt][i] = f32x4{0.f,0.f,0.f,0.f};
    #pragma unroll
    for (int ks=0; ks<KS; ++ks){
      #pragma unroll
      for (int i=0; i<PNT; ++i){
        int nt = p*PNT + i;
        u16x8 b = *(const u16x8*)&Bw[((size_t)(nt*KS + ks)*64 + lane)*8];
        acc[0][i] = mfma16(a[0][ks], b, acc[0][i]);
        acc[1][i] = mfma16(a[1][ks], b, acc[1][i]);
      }
    }
    #pragma unroll
    for (int i=0; i<PNT; ++i){
      int nt = p*PNT + i; int col = nt*16 + lr;
      float bv = bias[col];
      #pragma unroll
      for (int mt=0; mt<2; ++mt){
        #pragma unroll
        for (int q=0; q<4; ++q){
          size_t row = rb + mt*16 + lq + q;
          float v = acc[mt][i][q] + bv;
          if (MODE==1) v = __expf(-fmaxf(0.f, v));
          out[row*N + col] = f2bf(v);
        }
      }
    }
  }
}

// ---- persistent sequential kernel: pipelined stream + LDS residency ------
__global__ __launch_bounds__(512)
__attribute__((amdgpu_waves_per_eu(2, 2)))
void seq12(
    const unsigned short* __restrict__ WstrG, const unsigned short* __restrict__ WldsG,
    const unsigned short* __restrict__ gamma, const unsigned short* __restrict__ gipre,
    const float* __restrict__ bhh, float* __restrict__ out){
  extern __shared__ char smem[];
  unsigned short* Wlds = (unsigned short*)smem;            // 131072 B (ks4,5)
  unsigned short* hsw  = (unsigned short*)(smem + 131072); //   8192 B
  const int tid  = threadIdx.x;
  const int lane = tid & 63;
  const int w    = tid >> 6;              // 0..7
  const int bbase = blockIdx.x * 16;
  const int lr   = lane & 15;
  const int lq4  = (lane >> 4) << 2;

  // ---- prologue: LDS-resident ks4..5 (128 KB) ----
  for (int i = tid; i < 8192; i += 512)
    *(u16x8*)&Wlds[i*8] = *(const u16x8*)&WldsG[i*8];

  float h_reg[2][4];
  #pragma unroll
  for (int c=0; c<2; ++c)
    #pragma unroll
    for (int q=0; q<4; ++q) h_reg[c][q] = 0.f;

  float bnv[2];
  #pragma unroll
  for (int c=0; c<2; ++c) bnv[c] = bhh[512 + w*32 + c*16 + lr];

  unsigned short g_pre[2][4];
  #pragma unroll
  for (int c=0; c<2; ++c)
    #pragma unroll
    for (int q=0; q<4; ++q)
      g_pre[c][q] = gamma[((size_t)(bbase + lq4 + q))*256 + w*32 + c*16 + lr];

  const unsigned short* wsb = WstrG + (size_t)w*24576 + lane*8;

  __syncthreads();

  for (int t = 0; t < 128; ++t){
    // ---- phase 1: decay h, publish A-fragments ----
    #pragma unroll
    for (int c=0; c<2; ++c){
      const int col = w*32 + c*16 + lr;
      #pragma unroll
      for (int q=0; q<4; ++q){
        float hd = h_reg[c][q] * bf2f(g_pre[c][q]);
        h_reg[c][q] = hd;
        hsw[(col>>5)*512 + ((lq4+q) + (((col>>3)&3)<<4))*8 + (col&7)] = f2bf(hd);
      }
    }
    __syncthreads();   // S1: hsw ready

    // rep stores AFTER the barrier: drain overlaps the MFMA phase
    #pragma unroll
    for (int c=0; c<2; ++c){
      const int col = w*32 + c*16 + lr;
      #pragma unroll
      for (int q=0; q<4; ++q)
        out[((size_t)(bbase+lq4+q)*128 + t)*256 + col] = h_reg[c][q];
    }

    f32x4 acc[4][2];
    #pragma unroll
    for (int g=0; g<4; ++g)
      #pragma unroll
      for (int c=0; c<2; ++c) acc[g][c] = f32x4{0.f,0.f,0.f,0.f};

    // opaque per-iteration offset: defeats LICM/CSE so the stream loads
    // stay IN-LOOP in textual order (the whole point of this round)
    int off = 0;
    asm volatile("" : "+v"(off));
    const unsigned short* wp = wsb + off;

    u16x8 r0[8], r1[8], r2[8];
    #define ISS(r_, s_) { \
      _Pragma("unroll") \
      for (int i=0;i<8;++i) r_[i] = *(const u16x8*)(wp + ((s_)*8+i)*512); \
      } __builtin_amdgcn_sched_barrier(0);
    #define CONS(r_, ks_) { \
      u16x8 aR = *(const u16x8*)&hsw[(ks_)*512 + lane*8]; \
      _Pragma("unroll") \
      for (int i=0;i<8;++i) acc[i>>1][i&1] = mfma16(aR, r_[i], acc[i>>1][i&1]); \
      } __builtin_amdgcn_sched_barrier(0);

    ISS(r0,0) ISS(r1,1) ISS(r2,2)          // 24 chunks in flight
    CONS(r0,0) ISS(r0,3)
    CONS(r1,1) ISS(r1,4)
    CONS(r2,2) ISS(r2,5)

    // gate-input prefetch under batch-flight cover
    const unsigned short* gp = gipre + ((size_t)t*1024 + bbase)*768;
    unsigned short gv[3][2][4];
    #pragma unroll
    for (int g3=0; g3<3; ++g3)
      #pragma unroll
      for (int c=0; c<2; ++c)
        #pragma unroll
        for (int q=0; q<4; ++q)
          gv[g3][c][q] = gp[(size_t)(lq4+q)*768 + g3*256 + w*32 + c*16 + lr];
    if (t < 127){
      #pragma unroll
      for (int c=0; c<2; ++c)
        #pragma unroll
        for (int q=0; q<4; ++q)
          g_pre[c][q] = gamma[((size_t)(t+1)*1024 + bbase + lq4 + q)*256 + w*32 + c*16 + lr];
    }
    __builtin_amdgcn_sched_barrier(0);

    CONS(r0,3)
    // LDS-resident ks4..5 (16 MFMA) — covers tail of batches 4,5
    #pragma unroll
    for (int ks2=0; ks2<2; ++ks2){
      u16x8 aL = *(const u16x8*)&hsw[(4+ks2)*512 + lane*8];
      #pragma unroll
      for (int g=0; g<4; ++g)
        #pragma unroll
        for (int c=0; c<2; ++c){
          u16x8 bL = *(const u16x8*)&Wlds[((w*8+g*2+c)*2 + ks2)*512 + lane*8];
          acc[g][c] = mfma16(aL, bL, acc[g][c]);
        }
    }
    __builtin_amdgcn_sched_barrier(0);
    CONS(r1,6)
    CONS(r2,7)
    #undef ISS
    #undef CONS
    __syncthreads();   // S2: hsw reads done -> next phase1 may overwrite

    // ---- gate phase (in-register) ----
    #pragma unroll
    for (int c=0; c<2; ++c){
      const int col = w*32 + c*16 + lr;
      #pragma unroll
      for (int q=0; q<4; ++q){
        float gr = bf2f(gv[0][c][q]);
        float gz = bf2f(gv[1][c][q]);
        float gn = bf2f(gv[2][c][q]);
        float rr = sigm(gr + acc[0][c][q]);
        float zz = sigm(gz + acc[1][c][q]);
        float nv = tanh_f(gn + acc[2][c][q] + rr*(acc[3][c][q] + bnv[c]));
        float hn = (1.f-zz)*nv + zz*h_reg[c][q];
        h_reg[c][q] = hn;
        if (t == 127) out[(size_t)33554432 + (size_t)(bbase+lq4+q)*256 + col] = hn;
      }
    }
  }
}

// ---- host glue -----------------------------------------------------------
extern "C" void kernel_launch(void* const* d_in, const int* in_sizes, int n_in,
                              void* d_out, int out_size, void* d_ws, size_t ws_size,
                              hipStream_t stream){
  (void)in_sizes; (void)n_in; (void)out_size; (void)ws_size;
  const float* X   = (const float*)d_in[0];
  const float* M   = (const float*)d_in[1];
  const float* D   = (const float*)d_in[2];
  const float* mu  = (const float*)d_in[3];
  const float* Xl  = (const float*)d_in[4];
  const float* Wdh = (const float*)d_in[5];
  const float* bdh = (const float*)d_in[6];
  const float* Wdx = (const float*)d_in[7];
  const float* bdx = (const float*)d_in[8];
  const float* Wih = (const float*)d_in[9];
  const float* Whh = (const float*)d_in[10];
  const float* bih = (const float*)d_in[11];
  const float* bhh = (const float*)d_in[12];
  float* out = (float*)d_out;
  char* ws = (char*)d_ws;

  // workspace layout
  unsigned short* gipre = (unsigned short*)ws;                      // 201326592 B
  unsigned short* gamma = (unsigned short*)(ws + 201326592);        //  67108864 B
  unsigned short* W2sw  = (unsigned short*)(ws + 268435456);        //    393216 B
  unsigned short* Wdsw  = (unsigned short*)(ws + 268828672);        //     65536 B
  unsigned short* WstrG = (unsigned short*)(ws + 268894208);        //    393216 B
  unsigned short* WldsG = (unsigned short*)(ws + 269287424);        //    131072 B
  float*          b2    = (float*)        (ws + 269418496);         //      3072 B
  // Apre (67.1MB) + Dt (33.6MB) staged inside d_out: fully consumed by the
  // GEMMs below BEFORE seq12 writes the real outputs (same-stream ordering).
  unsigned short* Apre = (unsigned short*)d_out;
  unsigned short* Dt   = (unsigned short*)((char*)d_out + 67108864);

  hipFuncSetAttribute(reinterpret_cast<const void*>(seq12),
                      hipFuncAttributeMaxDynamicSharedMemorySize, 139264);

  kw<<<256, 256, 0, stream>>>(Wdh, Wih, Whh, bih, bhh, WstrG, WldsG, W2sw, Wdsw, b2);
  kprep<<<1024, 256, 0, stream>>>(X, M, D, mu, Xl, Wdx, bdx, Apre, Dt);
  gemm_act<4,16,8,1><<<1024, 256, 0, stream>>>(Dt, Wdsw, bdh, gamma);
  gemm_act<8,48,8,0><<<1024, 256, 0, stream>>>(Apre, W2sw, b2, gipre);
  seq12<<<64, 512, 139264, stream>>>(WstrG, WldsG, gamma, gipre, bhh, out);
}

// Round 15
// 915.684 us; speedup vs baseline: 5.5920x; 1.2804x over previous
//
#include <hip/hip_runtime.h>
#include <cstdint>
#include <cstddef>

typedef __attribute__((ext_vector_type(8))) __bf16 bf16x8;
typedef __attribute__((ext_vector_type(8))) unsigned short u16x8;
typedef __attribute__((ext_vector_type(4))) unsigned short u16x4;
typedef __attribute__((ext_vector_type(2))) unsigned short u16x2;
typedef __attribute__((ext_vector_type(4))) float f32x4;
typedef __attribute__((ext_vector_type(2))) float f32x2;

// ---- helpers -------------------------------------------------------------
__device__ __forceinline__ unsigned short f2bf(float f){
  unsigned int u = __float_as_uint(f);
  u += 0x7FFFu + ((u >> 16) & 1u);          // round to nearest even
  return (unsigned short)(u >> 16);
}
__device__ __forceinline__ float bf2f(unsigned short s){
  return __uint_as_float(((unsigned int)s) << 16);
}
__device__ __forceinline__ float sigm(float x){ return 1.f/(1.f + __expf(-x)); }
__device__ __forceinline__ float tanh_f(float x){ float e = __expf(2.f*x); return 1.f - 2.f/(e + 1.f); }
__device__ __forceinline__ f32x4 mfma16(u16x8 a, u16x8 b, f32x4 c){
  return __builtin_amdgcn_mfma_f32_16x16x32_bf16(
      __builtin_bit_cast(bf16x8, a), __builtin_bit_cast(bf16x8, b), c, 0, 0, 0);
}

// B=1024, T=128, F=128, H=256
// seq12 (UNCHANGED from round 14, 737us, verified): per-CU byte-throughput
// bound at ~31 B/cy with 432 KB/step/CU. This round attacks the prep chain:
// gemm_act re-read all of B per WAVE (1.57 TB L2 traffic for the 768-col
// GEMM). gemm_lds stages B in 64KB LDS shared by 8 waves -> 4-16x less.

__device__ __forceinline__ float wcval(int g, int n, int k,
    const float* __restrict__ Wih, const float* __restrict__ Whh){
  if (g==0) return Wih[n*512 + 128+k]       + Whh[n*256 + k];
  if (g==1) return Wih[(256+n)*512 + 128+k] + Whh[(256+n)*256 + k];
  if (g==2) return Wih[(512+n)*512 + 128+k];
  return Whh[(512+n)*256 + k];
}

// ---- weight prep (unchanged from round 14) -------------------------------
// WstrG: (((w*6+s)*8+i)*64+l)*8+j   s=0..5 -> ks_eff=[0,1,2,3,6,7][s],
//        g=i>>1, c=i&1, n=(w*2+c)*16+(l&15)   (196608 elems, 384 KB)
// WldsG: (((w*8+g*2+c)*2+ks2)*64+l)*8+j  ks=4+ks2 (65536 elems, 128 KB)
// W2  : [nt(48)][ks(8)][lane(64)][8] ; Wd : [nt(16)][ks(4)][lane(64)][8]
__global__ __launch_bounds__(256) void kw(
    const float* __restrict__ Wdh, const float* __restrict__ Wih,
    const float* __restrict__ Whh, const float* __restrict__ bih,
    const float* __restrict__ bhh,
    unsigned short* __restrict__ WstrG, unsigned short* __restrict__ WldsG,
    unsigned short* __restrict__ W2,
    unsigned short* __restrict__ Wd, float* __restrict__ b2){
  int i0 = blockIdx.x*256 + threadIdx.x;
  int stride = gridDim.x*256;
  for (int idx=i0; idx<196608; idx+=stride){          // WstrG (ks 0..3,6,7)
    int j=idx&7, l=(idx>>3)&63, r=idx>>9;             // r < 384
    int i=r&7, r2=r>>3;                               // r2 = w*6+s
    int s=r2%6, w=r2/6;
    int ks = (s<4) ? s : (s+2);
    int g=i>>1, c=i&1;
    int n = (w*2+c)*16 + (l&15);
    int k = ks*32 + ((l>>4)<<3) + j;
    WstrG[idx] = f2bf(wcval(g, n, k, Wih, Whh));
  }
  for (int idx=i0; idx<65536; idx+=stride){           // WldsG (ks 4..5)
    int j=idx&7, l=(idx>>3)&63, r=idx>>9;             // r < 128
    int ks2=r&1, r2=r>>1;
    int c=r2&1, g=(r2>>1)&3, w=r2>>3;
    int n = (w*2+c)*16 + (l&15);
    int k = (4+ks2)*32 + ((l>>4)<<3) + j;
    WldsG[idx] = f2bf(wcval(g, n, k, Wih, Whh));
  }
  for (int idx=i0; idx<196608; idx+=stride){
    int j=idx&7, l=(idx>>3)&63, ks=(idx>>9)&7, nt=idx>>12;
    int n = nt*16 + (l&15);
    int k = ks*32 + ((l>>4)<<3) + j;
    float v = (k<128) ? Wih[n*512 + k] : Wih[n*512 + 256 + k];
    W2[idx] = f2bf(v);
  }
  for (int idx=i0; idx<32768; idx+=stride){
    int j=idx&7, l=(idx>>3)&63, ks=(idx>>9)&3, nt=idx>>11;
    int n = nt*16 + (l&15);
    int k = ks*32 + ((l>>4)<<3) + j;
    Wd[idx] = f2bf(Wdh[n*128 + k]);
  }
  for (int idx=i0; idx<768; idx+=stride)
    b2[idx] = bih[idx] + (idx<512 ? bhh[idx] : 0.f);
}

// ---- elementwise prep (unchanged, verified) ------------------------------
__global__ __launch_bounds__(256) void kprep(
    const float* __restrict__ X, const float* __restrict__ M,
    const float* __restrict__ D, const float* __restrict__ mu,
    const float* __restrict__ Xl, const float* __restrict__ Wdx,
    const float* __restrict__ bdx,
    unsigned short* __restrict__ Apre, unsigned short* __restrict__ Dt){
  int lane = threadIdx.x & 63;
  int wave = (blockIdx.x*256 + threadIdx.x) >> 6;
  int c0 = lane*2;
  float dg0 = Wdx[c0*128 + c0];
  float dg1 = Wdx[(c0+1)*128 + (c0+1)];
  float bx0 = bdx[c0], bx1 = bdx[c0+1];
  for (int r = wave; r < 131072; r += 4096){
    int t = r>>10, b = r&1023;
    size_t src = ((size_t)b*128 + t)*128 + c0;
    f32x2 x  = *(const f32x2*)(X+src);
    f32x2 m  = *(const f32x2*)(M+src);
    f32x2 d  = *(const f32x2*)(D+src);
    f32x2 xl = *(const f32x2*)(Xl+src);
    f32x2 mb = *(const f32x2*)(mu + b*128 + c0);
    float g0 = __expf(-fmaxf(0.f, d.x*dg0 + bx0));
    float g1 = __expf(-fmaxf(0.f, d.y*dg1 + bx1));
    float xh0 = g0*xl.x + (1.f-g0)*mb.x;
    float xh1 = g1*xl.y + (1.f-g1)*mb.y;
    float xi0 = m.x*x.x + (1.f-m.x)*xh0;
    float xi1 = m.y*x.y + (1.f-m.y)*xh1;
    size_t ar = (size_t)r*256;
    *(u16x2*)(Apre + ar + c0)        = u16x2{f2bf(xi0), f2bf(xi1)};
    *(u16x2*)(Apre + ar + 128 + c0)  = u16x2{f2bf(m.x), f2bf(m.y)};
    *(u16x2*)(Dt + (size_t)r*128 + c0) = u16x2{f2bf(d.x), f2bf(d.y)};
  }
}

// ---- LDS-staged activation GEMM: 512 thr / 8 waves / 128 rows per block --
// Per pass: stage PNT*KS chunks (=64 chunks = 64 KB) of B into LDS, shared
// by all 8 waves. MODE 0: out=bf16(acc+bias); MODE 1: out=bf16(exp(-relu)).
template<int KS, int NTOT, int PNT, int MODE>
__global__ __launch_bounds__(512) void gemm_lds(
    const unsigned short* __restrict__ A, const unsigned short* __restrict__ Bw,
    const float* __restrict__ bias, unsigned short* __restrict__ out){
  extern __shared__ char smem[];
  unsigned short* Bs = (unsigned short*)smem;       // 65536 B
  const int N = NTOT*16;
  const int lane = threadIdx.x & 63;
  const int w    = threadIdx.x >> 6;
  const size_t rb = (size_t)blockIdx.x*128 + w*16;
  const int lr = lane&15, lk=(lane>>4)<<3, lq=(lane>>4)<<2;
  u16x8 a[KS];
  #pragma unroll
  for (int ks=0; ks<KS; ++ks)
    a[ks] = *(const u16x8*)&A[(rb + lr)*(KS*32) + ks*32 + lk];
  #pragma unroll
  for (int p=0; p<NTOT/PNT; ++p){
    __syncthreads();   // previous pass's Bs reads complete
    {
      const u16x8* src = (const u16x8*)&Bw[(size_t)p*PNT*KS*512];
      u16x8* dst = (u16x8*)Bs;
      #pragma unroll
      for (int i=0; i<8; ++i)                        // 4096 u16x8 / 512 thr
        dst[threadIdx.x + i*512] = src[threadIdx.x + i*512];
    }
    __syncthreads();   // Bs staged
    f32x4 acc[PNT];
    #pragma unroll
    for (int i=0; i<PNT; ++i) acc[i] = f32x4{0.f,0.f,0.f,0.f};
    #pragma unroll
    for (int ks=0; ks<KS; ++ks)
      #pragma unroll
      for (int i=0; i<PNT; ++i){
        u16x8 b = *(const u16x8*)&Bs[((i*KS + ks)*64 + lane)*8];
        acc[i] = mfma16(a[ks], b, acc[i]);
      }
    #pragma unroll
    for (int i=0; i<PNT; ++i){
      int col = (p*PNT + i)*16 + lr;
      float bv = bias[col];
      #pragma unroll
      for (int q=0; q<4; ++q){
        float v = acc[i][q] + bv;
        if (MODE==1) v = __expf(-fmaxf(0.f, v));
        out[(rb + lq + q)*(size_t)N + col] = f2bf(v);
      }
    }
  }
}

// ---- persistent sequential kernel (UNCHANGED from round 14, verified) ----
__global__ __launch_bounds__(512)
__attribute__((amdgpu_waves_per_eu(2, 2)))
void seq12(
    const unsigned short* __restrict__ WstrG, const unsigned short* __restrict__ WldsG,
    const unsigned short* __restrict__ gamma, const unsigned short* __restrict__ gipre,
    const float* __restrict__ bhh, float* __restrict__ out){
  extern __shared__ char smem[];
  unsigned short* Wlds = (unsigned short*)smem;            // 131072 B (ks4,5)
  unsigned short* hsw  = (unsigned short*)(smem + 131072); //   8192 B
  const int tid  = threadIdx.x;
  const int lane = tid & 63;
  const int w    = tid >> 6;              // 0..7
  const int bbase = blockIdx.x * 16;
  const int lr   = lane & 15;
  const int lq4  = (lane >> 4) << 2;

  for (int i = tid; i < 8192; i += 512)
    *(u16x8*)&Wlds[i*8] = *(const u16x8*)&WldsG[i*8];

  float h_reg[2][4];
  #pragma unroll
  for (int c=0; c<2; ++c)
    #pragma unroll
    for (int q=0; q<4; ++q) h_reg[c][q] = 0.f;

  float bnv[2];
  #pragma unroll
  for (int c=0; c<2; ++c) bnv[c] = bhh[512 + w*32 + c*16 + lr];

  unsigned short g_pre[2][4];
  #pragma unroll
  for (int c=0; c<2; ++c)
    #pragma unroll
    for (int q=0; q<4; ++q)
      g_pre[c][q] = gamma[((size_t)(bbase + lq4 + q))*256 + w*32 + c*16 + lr];

  const unsigned short* wsb = WstrG + (size_t)w*24576 + lane*8;

  __syncthreads();

  for (int t = 0; t < 128; ++t){
    #pragma unroll
    for (int c=0; c<2; ++c){
      const int col = w*32 + c*16 + lr;
      #pragma unroll
      for (int q=0; q<4; ++q){
        float hd = h_reg[c][q] * bf2f(g_pre[c][q]);
        h_reg[c][q] = hd;
        hsw[(col>>5)*512 + ((lq4+q) + (((col>>3)&3)<<4))*8 + (col&7)] = f2bf(hd);
      }
    }
    __syncthreads();   // S1: hsw ready

    #pragma unroll
    for (int c=0; c<2; ++c){
      const int col = w*32 + c*16 + lr;
      #pragma unroll
      for (int q=0; q<4; ++q)
        out[((size_t)(bbase+lq4+q)*128 + t)*256 + col] = h_reg[c][q];
    }

    f32x4 acc[4][2];
    #pragma unroll
    for (int g=0; g<4; ++g)
      #pragma unroll
      for (int c=0; c<2; ++c) acc[g][c] = f32x4{0.f,0.f,0.f,0.f};

    int off = 0;
    asm volatile("" : "+v"(off));
    const unsigned short* wp = wsb + off;

    u16x8 r0[8], r1[8], r2[8];
    #define ISS(r_, s_) { \
      _Pragma("unroll") \
      for (int i=0;i<8;++i) r_[i] = *(const u16x8*)(wp + ((s_)*8+i)*512); \
      } __builtin_amdgcn_sched_barrier(0);
    #define CONS(r_, ks_) { \
      u16x8 aR = *(const u16x8*)&hsw[(ks_)*512 + lane*8]; \
      _Pragma("unroll") \
      for (int i=0;i<8;++i) acc[i>>1][i&1] = mfma16(aR, r_[i], acc[i>>1][i&1]); \
      } __builtin_amdgcn_sched_barrier(0);

    ISS(r0,0) ISS(r1,1) ISS(r2,2)
    CONS(r0,0) ISS(r0,3)
    CONS(r1,1) ISS(r1,4)
    CONS(r2,2) ISS(r2,5)

    const unsigned short* gp = gipre + ((size_t)t*1024 + bbase)*768;
    unsigned short gv[3][2][4];
    #pragma unroll
    for (int g3=0; g3<3; ++g3)
      #pragma unroll
      for (int c=0; c<2; ++c)
        #pragma unroll
        for (int q=0; q<4; ++q)
          gv[g3][c][q] = gp[(size_t)(lq4+q)*768 + g3*256 + w*32 + c*16 + lr];
    if (t < 127){
      #pragma unroll
      for (int c=0; c<2; ++c)
        #pragma unroll
        for (int q=0; q<4; ++q)
          g_pre[c][q] = gamma[((size_t)(t+1)*1024 + bbase + lq4 + q)*256 + w*32 + c*16 + lr];
    }
    __builtin_amdgcn_sched_barrier(0);

    CONS(r0,3)
    #pragma unroll
    for (int ks2=0; ks2<2; ++ks2){
      u16x8 aL = *(const u16x8*)&hsw[(4+ks2)*512 + lane*8];
      #pragma unroll
      for (int g=0; g<4; ++g)
        #pragma unroll
        for (int c=0; c<2; ++c){
          u16x8 bL = *(const u16x8*)&Wlds[((w*8+g*2+c)*2 + ks2)*512 + lane*8];
          acc[g][c] = mfma16(aL, bL, acc[g][c]);
        }
    }
    __builtin_amdgcn_sched_barrier(0);
    CONS(r1,6)
    CONS(r2,7)
    #undef ISS
    #undef CONS
    __syncthreads();   // S2

    #pragma unroll
    for (int c=0; c<2; ++c){
      const int col = w*32 + c*16 + lr;
      #pragma unroll
      for (int q=0; q<4; ++q){
        float gr = bf2f(gv[0][c][q]);
        float gz = bf2f(gv[1][c][q]);
        float gn = bf2f(gv[2][c][q]);
        float rr = sigm(gr + acc[0][c][q]);
        float zz = sigm(gz + acc[1][c][q]);
        float nv = tanh_f(gn + acc[2][c][q] + rr*(acc[3][c][q] + bnv[c]));
        float hn = (1.f-zz)*nv + zz*h_reg[c][q];
        h_reg[c][q] = hn;
        if (t == 127) out[(size_t)33554432 + (size_t)(bbase+lq4+q)*256 + col] = hn;
      }
    }
  }
}

// ---- host glue -----------------------------------------------------------
extern "C" void kernel_launch(void* const* d_in, const int* in_sizes, int n_in,
                              void* d_out, int out_size, void* d_ws, size_t ws_size,
                              hipStream_t stream){
  (void)in_sizes; (void)n_in; (void)out_size; (void)ws_size;
  const float* X   = (const float*)d_in[0];
  const float* M   = (const float*)d_in[1];
  const float* D   = (const float*)d_in[2];
  const float* mu  = (const float*)d_in[3];
  const float* Xl  = (const float*)d_in[4];
  const float* Wdh = (const float*)d_in[5];
  const float* bdh = (const float*)d_in[6];
  const float* Wdx = (const float*)d_in[7];
  const float* bdx = (const float*)d_in[8];
  const float* Wih = (const float*)d_in[9];
  const float* Whh = (const float*)d_in[10];
  const float* bih = (const float*)d_in[11];
  const float* bhh = (const float*)d_in[12];
  float* out = (float*)d_out;
  char* ws = (char*)d_ws;

  // workspace layout
  unsigned short* gipre = (unsigned short*)ws;                      // 201326592 B
  unsigned short* gamma = (unsigned short*)(ws + 201326592);        //  67108864 B
  unsigned short* W2sw  = (unsigned short*)(ws + 268435456);        //    393216 B
  unsigned short* Wdsw  = (unsigned short*)(ws + 268828672);        //     65536 B
  unsigned short* WstrG = (unsigned short*)(ws + 268894208);        //    393216 B
  unsigned short* WldsG = (unsigned short*)(ws + 269287424);        //    131072 B
  float*          b2    = (float*)        (ws + 269418496);         //      3072 B
  // Apre (67.1MB) + Dt (33.6MB) staged inside d_out: fully consumed by the
  // GEMMs below BEFORE seq12 writes the real outputs (same-stream ordering).
  unsigned short* Apre = (unsigned short*)d_out;
  unsigned short* Dt   = (unsigned short*)((char*)d_out + 67108864);

  hipFuncSetAttribute(reinterpret_cast<const void*>(seq12),
                      hipFuncAttributeMaxDynamicSharedMemorySize, 139264);
  hipFuncSetAttribute(reinterpret_cast<const void*>(&gemm_lds<4,16,16,1>),
                      hipFuncAttributeMaxDynamicSharedMemorySize, 65536);
  hipFuncSetAttribute(reinterpret_cast<const void*>(&gemm_lds<8,48,8,0>),
                      hipFuncAttributeMaxDynamicSharedMemorySize, 65536);

  kw<<<256, 256, 0, stream>>>(Wdh, Wih, Whh, bih, bhh, WstrG, WldsG, W2sw, Wdsw, b2);
  kprep<<<1024, 256, 0, stream>>>(X, M, D, mu, Xl, Wdx, bdx, Apre, Dt);
  gemm_lds<4,16,16,1><<<1024, 512, 65536, stream>>>(Dt, Wdsw, bdh, gamma);
  gemm_lds<8,48,8,0><<<1024, 512, 65536, stream>>>(Apre, W2sw, b2, gipre);
  seq12<<<64, 512, 139264, stream>>>(WstrG, WldsG, gamma, gipre, bhh, out);
}